// Round 5
// baseline (366.198 us; speedup 1.0000x reference)
//
#include <hip/hip_runtime.h>
#include <math.h>

#define NW 12
#define NL 4
#define DIM 4096

typedef float v2f __attribute__((ext_vector_type(2)));      // fp32 {re,im} (setup only)
typedef _Float16 h2 __attribute__((ext_vector_type(2)));    // f16 {re,im} amp

__device__ __forceinline__ v2f cmul(v2f a, v2f b){
    v2f d; d.x = a.x*b.x - a.y*b.y; d.y = a.x*b.y + a.y*b.x; return d;
}

// ---- packed f16 complex primitives (v_pk_*_f16, 2 cyc/wave64) ----
// d = { a.re*u.re, a.im*u.re }
__device__ __forceinline__ h2 cx_mul_re(h2 a, h2 u){
    h2 d;
    asm("v_pk_mul_f16 %0, %1, %2 op_sel:[0,0] op_sel_hi:[1,0]"
        : "=v"(d) : "v"(a), "v"(u));
    return d;
}
// d = acc + { a.re*u.re, a.im*u.re }
__device__ __forceinline__ h2 cx_fma_re(h2 a, h2 u, h2 acc){
    h2 d;
    asm("v_pk_fma_f16 %0, %1, %2, %3 op_sel:[0,0,0] op_sel_hi:[1,0,1]"
        : "=v"(d) : "v"(a), "v"(u), "v"(acc));
    return d;
}
// d = acc + { -a.im*u.im, a.re*u.im }
__device__ __forceinline__ h2 cx_fma_im(h2 a, h2 u, h2 acc){
    h2 d;
    asm("v_pk_fma_f16 %0, %1, %2, %3 op_sel:[1,1,0] op_sel_hi:[0,1,1] neg_lo:[0,1,0]"
        : "=v"(d) : "v"(a), "v"(u), "v"(acc));
    return d;
}

struct alignas(16) G16 { h2 u00, u01, u10, u11; };   // 16 B -> one ds_read_b128

// butterfly over the 16 register-resident amps on local bit mask m
__device__ __forceinline__ void bflys(h2 s[16], const G16& g, const int m){
    const h2 u00 = g.u00, u01 = g.u01, u10 = g.u10, u11 = g.u11;
    #pragma unroll
    for (int r = 0; r < 16; ++r) if (!(r & m)) {
        const h2 a = s[r], b = s[r|m];
        h2 na = cx_fma_im(a, u00, cx_mul_re(a, u00));
        na    = cx_fma_im(b, u01, cx_fma_re(b, u01, na));
        h2 nb = cx_fma_im(a, u10, cx_mul_re(a, u10));
        nb    = cx_fma_im(b, u11, cx_fma_re(b, u11, nb));
        s[r] = na; s[r|m] = nb;
    }
}
__device__ __forceinline__ void seg4(h2 s[16], const G16* g4){
    bflys(s, g4[0], 8);
    bflys(s, g4[1], 4);
    bflys(s, g4[2], 2);
    bflys(s, g4[3], 1);
}

__global__ __launch_bounds__(256, 8) void qnn_kernel(const float* __restrict__ x,
                                                     const float* __restrict__ w,
                                                     float* __restrict__ out)
{
    __shared__ h2 st[DIM + (DIM >> 4)];   // 4352 * 4 B = 17.4 KB, PHYS(i)=i+(i>>4)
    __shared__ G16 ug[NL * NW];           // 768 B
    __shared__ float sred[32];

    const int b = blockIdx.x;
    const int t = threadIdx.x;
    const int th = t >> 4, tl = t & 15;

    // ---- build fused per-(layer,wire) gate in fp32: U = Rz(w2)*Ry(w1)*Rx(w0)*Enc ----
    if (t < NL * NW) {
        const int wire = t % NW;
        const float ang = (wire & 1) ? x[b * 2 + 1] : x[b * 2 + 0];
        float se, ce;
        sincosf(0.5f * ang, &se, &ce);
        v2f E0, E1, E2, E3;
        if ((wire & 1) == 0) {            // Rx(x0)
            E0 = (v2f){ce, 0.f};  E1 = (v2f){0.f, -se};
            E2 = (v2f){0.f, -se}; E3 = (v2f){ce, 0.f};
        } else {                          // Ry(x1)
            E0 = (v2f){ce, 0.f};  E1 = (v2f){-se, 0.f};
            E2 = (v2f){se, 0.f};  E3 = (v2f){ce, 0.f};
        }
        const float w0 = w[t * 3 + 0];
        const float w1 = w[t * 3 + 1];
        const float w2 = w[t * 3 + 2];
        float s0, c0; sincosf(0.5f * w0, &s0, &c0);
        const v2f rx00 = (v2f){c0, 0.f}, rx01 = (v2f){0.f, -s0};
        v2f A0 = cmul(rx00, E0) + cmul(rx01, E2);
        v2f A1 = cmul(rx00, E1) + cmul(rx01, E3);
        v2f A2 = cmul(rx01, E0) + cmul(rx00, E2);
        v2f A3 = cmul(rx01, E1) + cmul(rx00, E3);
        float s1, c1; sincosf(0.5f * w1, &s1, &c1);
        v2f B0 = c1*A0 - s1*A2;
        v2f B1 = c1*A1 - s1*A3;
        v2f B2 = s1*A0 + c1*A2;
        v2f B3 = s1*A1 + c1*A3;
        float s2, c2; sincosf(0.5f * w2, &s2, &c2);
        const v2f em = (v2f){c2, -s2}, ep = (v2f){c2, s2};
        const v2f u00 = cmul(em, B0), u01 = cmul(em, B1);
        const v2f u10 = cmul(ep, B2), u11 = cmul(ep, B3);
        G16 gg;
        gg.u00 = (h2){(_Float16)u00.x, (_Float16)u00.y};
        gg.u01 = (h2){(_Float16)u01.x, (_Float16)u01.y};
        gg.u10 = (h2){(_Float16)u10.x, (_Float16)u10.y};
        gg.u11 = (h2){(_Float16)u11.x, (_Float16)u11.y};
        ug[t] = gg;
    }
    __syncthreads();

    // fp32 copies of layer-0 gate columns (needed before f16 rounding)
    // ---- layer 0 analytically in fp32: product state, CNOT(gray) baked into A layout ----
    // layout A: s[j] = amp at n = 16t + j
    h2 s[16];
    {
        // recompute layer-0 columns in fp32 from ug would lose precision; instead
        // rebuild the needed column entries in fp32 directly:
        // (cheap: reuse the f16 gates would inject early rounding; fp32 here)
        v2f col[12];   // chosen column entry per wire: u10 or u00 depending on bit
        const int u = (t ^ (t >> 1)) & 255;     // gray n bits 11..4 (wires 0..7)
        #pragma unroll
        for (int wq = 0; wq < 12; ++wq) {
            const int wire = wq;
            const float ang = (wire & 1) ? x[b * 2 + 1] : x[b * 2 + 0];
            float se, ce; sincosf(0.5f * ang, &se, &ce);
            v2f E0, E2;
            if ((wire & 1) == 0) { E0 = (v2f){ce, 0.f}; E2 = (v2f){0.f, -se}; }
            else                 { E0 = (v2f){ce, 0.f}; E2 = (v2f){se, 0.f};  }
            const float w0 = w[wq * 3 + 0];
            const float w1 = w[wq * 3 + 1];
            const float w2 = w[wq * 3 + 2];
            float s0, c0; sincosf(0.5f * w0, &s0, &c0);
            const v2f rx00 = (v2f){c0, 0.f}, rx01 = (v2f){0.f, -s0};
            v2f A0c = cmul(rx00, E0) + cmul(rx01, E2);   // col0 row0
            v2f A2c = cmul(rx01, E0) + cmul(rx00, E2);   // col0 row1
            float s1, c1; sincosf(0.5f * w1, &s1, &c1);
            v2f B0c = c1*A0c - s1*A2c;
            v2f B2c = s1*A0c + c1*A2c;
            float s2, c2; sincosf(0.5f * w2, &s2, &c2);
            const v2f em = (v2f){c2, -s2}, ep = (v2f){c2, s2};
            // col[wq][row0] = em*B0c (u00), [row1] = ep*B2c (u10)
            if (wq < 8) {
                const int bit = (u >> (7 - wq)) & 1;
                col[wq] = bit ? cmul(ep, B2c) : cmul(em, B0c);
            } else {
                col[wq]     = cmul(em, B0c);       // u00
                // store u10 in upper slots via second array below
            }
            // for wires 8..11 we need both entries; handle after loop
        }
        // recompute u10 entries for wires 8..11 (both column rows needed)
        v2f c10[4];
        #pragma unroll
        for (int wq = 8; wq < 12; ++wq) {
            const int wire = wq;
            const float ang = (wire & 1) ? x[b * 2 + 1] : x[b * 2 + 0];
            float se, ce; sincosf(0.5f * ang, &se, &ce);
            v2f E0, E2;
            if ((wire & 1) == 0) { E0 = (v2f){ce, 0.f}; E2 = (v2f){0.f, -se}; }
            else                 { E0 = (v2f){ce, 0.f}; E2 = (v2f){se, 0.f};  }
            const float w0 = w[wq * 3 + 0];
            const float w1 = w[wq * 3 + 1];
            const float w2 = w[wq * 3 + 2];
            float s0, c0; sincosf(0.5f * w0, &s0, &c0);
            const v2f rx00 = (v2f){c0, 0.f}, rx01 = (v2f){0.f, -s0};
            v2f A0c = cmul(rx00, E0) + cmul(rx01, E2);
            v2f A2c = cmul(rx01, E0) + cmul(rx00, E2);
            float s1, c1; sincosf(0.5f * w1, &s1, &c1);
            v2f B2c = s1*A0c + c1*A2c;
            float s2, c2; sincosf(0.5f * w2, &s2, &c2);
            const v2f ep = (v2f){c2, s2};
            c10[wq - 8] = cmul(ep, B2c);
        }
        v2f Pb = (v2f){1.f, 0.f};
        #pragma unroll
        for (int wq = 0; wq < 8; ++wq) Pb = cmul(Pb, col[wq]);
        v2f L2[4], T4[4];
        #pragma unroll
        for (int k = 0; k < 4; ++k) {
            L2[k] = cmul(((k >> 1) & 1) ? c10[0] : col[8],
                         (k & 1)        ? c10[1] : col[9]);
            T4[k] = cmul(((k >> 1) & 1) ? c10[2] : col[10],
                         (k & 1)        ? c10[3] : col[11]);
        }
        const int t0 = t & 1;
        #pragma unroll
        for (int j = 0; j < 16; ++j) {
            const int l0 = j ^ (j >> 1);
            const v2f Lsel = L2[((l0 >> 2) & 3) ^ (t0 ? 2 : 0)];
            const v2f amp = cmul(Pb, cmul(Lsel, T4[l0 & 3]));
            s[j] = (h2){(_Float16)amp.x, (_Float16)amp.y};
        }
    }

    // ---- layers 1..3: LDS-relayout segments, packed-f16 butterflies ----
    for (int layer = 1; layer < NL; ++layer) {
        const int gbase = layer * NW;

        // segment A: wires 8..11 — skipped in the last layer (can't affect
        // the marginal over wires 0..7, which fully determines all 8 outputs)
        if (layer < NL - 1) seg4(s, &ug[gbase + 8]);

        // T1: A -> C
        if (layer > 1) __syncthreads();   // protect prior layer's perm-gather reads
        #pragma unroll
        for (int r = 0; r < 16; ++r) st[17*t + r] = s[r];
        __syncthreads();
        #pragma unroll
        for (int r = 0; r < 16; ++r) s[r] = st[272*th + 17*r + tl];

        // segment C: wires 4..7
        seg4(s, &ug[gbase + 4]);

        // T2: C -> B (write back to slots just read -> no pre-sync)
        #pragma unroll
        for (int r = 0; r < 16; ++r) st[272*th + 17*r + tl] = s[r];
        __syncthreads();
        #pragma unroll
        for (int r = 0; r < 16; ++r) s[r] = st[272*r + t + th];

        // segment B: wires 0..3
        seg4(s, &ug[gbase + 0]);

        if (layer < NL - 1) {
            // T3: B -> A with CNOT perm fused (new[n] = old[n ^ (n>>1)])
            #pragma unroll
            for (int r = 0; r < 16; ++r) st[272*r + t + th] = s[r];
            __syncthreads();
            #pragma unroll
            for (int r = 0; r < 16; ++r) {
                const int n = (t << 4) | r;
                const int g = n ^ (n >> 1);
                s[r] = st[g + (g >> 4)];
            }
        }
    }

    // ---- reduction; final CNOT folded into signs (partial Walsh tree, fp32) ----
    // state layout B: n = (j<<8) | t ; wires 0..3 signs from j, wires 4..7 from t
    float p[16];
    #pragma unroll
    for (int r = 0; r < 16; ++r) {
        const float re = (float)s[r].x, im = (float)s[r].y;
        p[r] = re*re + im*im;
    }
    float s0[8], d0[8];
    #pragma unroll
    for (int k = 0; k < 8; ++k) { s0[k] = p[2*k] + p[2*k+1]; d0[k] = p[2*k] - p[2*k+1]; }
    float s1[4], ds1[4], dd1[4];
    #pragma unroll
    for (int k = 0; k < 4; ++k) {
        s1[k]  = s0[2*k] + s0[2*k+1];
        ds1[k] = s0[2*k] - s0[2*k+1];
        dd1[k] = d0[2*k] - d0[2*k+1];
    }
    const float A0 = (s1[0]  + s1[1])  - (s1[2]  + s1[3]);
    const float A1 = (s1[0]  - s1[1])  - (s1[2]  - s1[3]);
    const float A2 = (ds1[0] - ds1[1]) - (ds1[2] - ds1[3]);
    const float A3 = (dd1[0] - dd1[1]) - (dd1[2] - dd1[3]);

    float vals[8];
    vals[0] = A0; vals[1] = A1; vals[2] = A2; vals[3] = A3;
    const int t7 = (t >> 7) & 1, t6 = (t >> 6) & 1, t5 = (t >> 5) & 1, t4 = (t >> 4) & 1;
    vals[4] = t7            ? -A3 : A3;
    vals[5] = (t7^t6)       ? -A3 : A3;
    vals[6] = (t7^t6^t5)    ? -A3 : A3;
    vals[7] = (t7^t6^t5^t4) ? -A3 : A3;

    const int lane = t & 63, wv = t >> 6;
    #pragma unroll
    for (int i = 0; i < 8; ++i) {
        float v = vals[i];
        #pragma unroll
        for (int off = 32; off; off >>= 1) v += __shfl_xor(v, off, 64);
        if (lane == 0) sred[wv * 8 + i] = v;
    }
    __syncthreads();
    if (t < 8) {
        const float r = sred[t] + sred[8 + t] + sred[16 + t] + sred[24 + t];
        out[b * 8 + t] = r * 3.14159265358979323846f;
    }
}

extern "C" void kernel_launch(void* const* d_in, const int* in_sizes, int n_in,
                              void* d_out, int out_size, void* d_ws, size_t ws_size,
                              hipStream_t stream) {
    const float* x = (const float*)d_in[0];   // [4096, 2]
    const float* w = (const float*)d_in[1];   // [4, 12, 3]
    float* out = (float*)d_out;               // [4096, 8]
    qnn_kernel<<<4096, 256, 0, stream>>>(x, w, out);
}

// Round 6
// 134.153 us; speedup vs baseline: 2.7297x; 2.7297x over previous
//
#include <hip/hip_runtime.h>
#include <math.h>

#define NW 12
#define NL 4
#define DIM 4096

typedef float v2f __attribute__((ext_vector_type(2)));      // fp32 {re,im} (setup only)
typedef _Float16 h2 __attribute__((ext_vector_type(2)));    // f16 {re,im} amp

__device__ __forceinline__ v2f cmul(v2f a, v2f b){
    v2f d; d.x = a.x*b.x - a.y*b.y; d.y = a.x*b.y + a.y*b.x; return d;
}

// ---- packed f16 complex primitives (HW-validated in R5) ----
// d = { a.re*u.re, a.im*u.re }
__device__ __forceinline__ h2 cx_mul_re(h2 a, h2 u){
    h2 d;
    asm("v_pk_mul_f16 %0, %1, %2 op_sel:[0,0] op_sel_hi:[1,0]"
        : "=v"(d) : "v"(a), "v"(u));
    return d;
}
// d = acc + { a.re*u.re, a.im*u.re }
__device__ __forceinline__ h2 cx_fma_re(h2 a, h2 u, h2 acc){
    h2 d;
    asm("v_pk_fma_f16 %0, %1, %2, %3 op_sel:[0,0,0] op_sel_hi:[1,0,1]"
        : "=v"(d) : "v"(a), "v"(u), "v"(acc));
    return d;
}
// d = acc + { -a.im*u.im, a.re*u.im }
__device__ __forceinline__ h2 cx_fma_im(h2 a, h2 u, h2 acc){
    h2 d;
    asm("v_pk_fma_f16 %0, %1, %2, %3 op_sel:[1,1,0] op_sel_hi:[0,1,1] neg_lo:[0,1,0]"
        : "=v"(d) : "v"(a), "v"(u), "v"(acc));
    return d;
}

struct alignas(16) G16 { h2 u00, u01, u10, u11; };   // 16 B

__device__ __forceinline__ void bflys(h2 s[16], const G16& g, const int m){
    const h2 u00 = g.u00, u01 = g.u01, u10 = g.u10, u11 = g.u11;
    #pragma unroll
    for (int r = 0; r < 16; ++r) if (!(r & m)) {
        const h2 a = s[r], b = s[r|m];
        h2 na = cx_fma_im(a, u00, cx_mul_re(a, u00));
        na    = cx_fma_im(b, u01, cx_fma_re(b, u01, na));
        h2 nb = cx_fma_im(a, u10, cx_mul_re(a, u10));
        nb    = cx_fma_im(b, u11, cx_fma_re(b, u11, nb));
        s[r] = na; s[r|m] = nb;
    }
}
__device__ __forceinline__ void seg4(h2 s[16], const G16* g4){
    bflys(s, g4[0], 8);
    bflys(s, g4[1], 4);
    bflys(s, g4[2], 2);
    bflys(s, g4[3], 1);
}

__global__ __launch_bounds__(256, 8) void qnn_kernel(const float* __restrict__ x,
                                                     const float* __restrict__ w,
                                                     float* __restrict__ out)
{
    __shared__ h2 st[DIM + (DIM >> 4)];   // 4352 * 4 B = 17 KB, PHYS(i)=i+(i>>4)
    __shared__ G16 ug[NL * NW];           // 768 B (f16 gates, layers 1..3)
    __shared__ v2f g0c[NW][2];            // 192 B: layer-0 fp32 columns [wire][row]
    __shared__ float sred[32];

    const int b = blockIdx.x;
    const int t = threadIdx.x;
    const int th = t >> 4, tl = t & 15;

    // ---- build fused per-(layer,wire) gate in fp32: U = Rz(w2)*Ry(w1)*Rx(w0)*Enc ----
    if (t < NL * NW) {
        const int wire = t % NW;
        const float ang = (wire & 1) ? x[b * 2 + 1] : x[b * 2 + 0];
        float se, ce;
        sincosf(0.5f * ang, &se, &ce);
        v2f E0, E1, E2, E3;
        if ((wire & 1) == 0) {            // Rx(x0)
            E0 = (v2f){ce, 0.f};  E1 = (v2f){0.f, -se};
            E2 = (v2f){0.f, -se}; E3 = (v2f){ce, 0.f};
        } else {                          // Ry(x1)
            E0 = (v2f){ce, 0.f};  E1 = (v2f){-se, 0.f};
            E2 = (v2f){se, 0.f};  E3 = (v2f){ce, 0.f};
        }
        const float w0 = w[t * 3 + 0];
        const float w1 = w[t * 3 + 1];
        const float w2 = w[t * 3 + 2];
        float s0, c0; sincosf(0.5f * w0, &s0, &c0);
        const v2f rx00 = (v2f){c0, 0.f}, rx01 = (v2f){0.f, -s0};
        v2f A0 = cmul(rx00, E0) + cmul(rx01, E2);
        v2f A1 = cmul(rx00, E1) + cmul(rx01, E3);
        v2f A2 = cmul(rx01, E0) + cmul(rx00, E2);
        v2f A3 = cmul(rx01, E1) + cmul(rx00, E3);
        float s1, c1; sincosf(0.5f * w1, &s1, &c1);
        v2f B0 = c1*A0 - s1*A2;
        v2f B1 = c1*A1 - s1*A3;
        v2f B2 = s1*A0 + c1*A2;
        v2f B3 = s1*A1 + c1*A3;
        float s2, c2; sincosf(0.5f * w2, &s2, &c2);
        const v2f em = (v2f){c2, -s2}, ep = (v2f){c2, s2};
        const v2f u00 = cmul(em, B0), u01 = cmul(em, B1);
        const v2f u10 = cmul(ep, B2), u11 = cmul(ep, B3);
        G16 gg;
        gg.u00 = (h2){(_Float16)u00.x, (_Float16)u00.y};
        gg.u01 = (h2){(_Float16)u01.x, (_Float16)u01.y};
        gg.u10 = (h2){(_Float16)u10.x, (_Float16)u10.y};
        gg.u11 = (h2){(_Float16)u11.x, (_Float16)u11.y};
        ug[t] = gg;
        if (t < NW) {                     // layer-0 needs fp32 columns only
            g0c[t][0] = u00;
            g0c[t][1] = u10;
        }
    }
    __syncthreads();

    // ---- layer 0 analytically in fp32 (from shared columns), CNOT(gray) baked in ----
    // layout A: s[j] = amp at n = 16t + j
    h2 s[16];
    {
        const int u = (t ^ (t >> 1)) & 255;     // gray n bits 11..4 (wires 0..7)
        v2f Pb = (v2f){1.f, 0.f};
        #pragma unroll
        for (int wq = 0; wq < 8; ++wq)
            Pb = cmul(Pb, g0c[wq][(u >> (7 - wq)) & 1]);
        v2f L2[4], T4[4];
        #pragma unroll
        for (int k = 0; k < 4; ++k) {
            L2[k] = cmul(g0c[8][(k >> 1) & 1],  g0c[9][k & 1]);
            T4[k] = cmul(g0c[10][(k >> 1) & 1], g0c[11][k & 1]);
        }
        const int t0 = t & 1;
        #pragma unroll
        for (int j = 0; j < 16; ++j) {
            const int l0 = j ^ (j >> 1);
            const v2f Lsel = L2[((l0 >> 2) & 3) ^ (t0 ? 2 : 0)];
            const v2f amp = cmul(Pb, cmul(Lsel, T4[l0 & 3]));
            s[j] = (h2){(_Float16)amp.x, (_Float16)amp.y};
        }
    }

    // ---- layers 1..3: LDS-relayout segments, packed-f16 butterflies ----
    for (int layer = 1; layer < NL; ++layer) {
        const int gbase = layer * NW;

        // segment A: wires 8..11 — skipped in last layer (unitary on bits 3..0
        // preserves the bits-11..4 marginal, which determines all 8 outputs)
        if (layer < NL - 1) seg4(s, &ug[gbase + 8]);

        // T1: A -> C
        if (layer > 1) __syncthreads();   // protect prior layer's perm-gather reads
        #pragma unroll
        for (int r = 0; r < 16; ++r) st[17*t + r] = s[r];
        __syncthreads();
        #pragma unroll
        for (int r = 0; r < 16; ++r) s[r] = st[272*th + 17*r + tl];

        // segment C: wires 4..7
        seg4(s, &ug[gbase + 4]);

        // T2: C -> B (write back to slots just read -> no pre-sync)
        #pragma unroll
        for (int r = 0; r < 16; ++r) st[272*th + 17*r + tl] = s[r];
        __syncthreads();
        #pragma unroll
        for (int r = 0; r < 16; ++r) s[r] = st[272*r + t + th];

        // segment B: wires 0..3
        seg4(s, &ug[gbase + 0]);

        if (layer < NL - 1) {
            // T3: B -> A with CNOT perm fused (new[n] = old[n ^ (n>>1)])
            #pragma unroll
            for (int r = 0; r < 16; ++r) st[272*r + t + th] = s[r];
            __syncthreads();
            #pragma unroll
            for (int r = 0; r < 16; ++r) {
                const int n = (t << 4) | r;
                const int g = n ^ (n >> 1);
                s[r] = st[g + (g >> 4)];
            }
        }
    }

    // ---- reduction; final CNOT folded into signs (partial Walsh tree, fp32) ----
    // state layout B: n = (j<<8) | t
    float p[16];
    #pragma unroll
    for (int r = 0; r < 16; ++r) {
        const float re = (float)s[r].x, im = (float)s[r].y;
        p[r] = re*re + im*im;
    }
    float s0[8], d0[8];
    #pragma unroll
    for (int k = 0; k < 8; ++k) { s0[k] = p[2*k] + p[2*k+1]; d0[k] = p[2*k] - p[2*k+1]; }
    float s1[4], ds1[4], dd1[4];
    #pragma unroll
    for (int k = 0; k < 4; ++k) {
        s1[k]  = s0[2*k] + s0[2*k+1];
        ds1[k] = s0[2*k] - s0[2*k+1];
        dd1[k] = d0[2*k] - d0[2*k+1];
    }
    const float A0 = (s1[0]  + s1[1])  - (s1[2]  + s1[3]);
    const float A1 = (s1[0]  - s1[1])  - (s1[2]  - s1[3]);
    const float A2 = (ds1[0] - ds1[1]) - (ds1[2] - ds1[3]);
    const float A3 = (dd1[0] - dd1[1]) - (dd1[2] - dd1[3]);

    float vals[8];
    vals[0] = A0; vals[1] = A1; vals[2] = A2; vals[3] = A3;
    const int t7 = (t >> 7) & 1, t6 = (t >> 6) & 1, t5 = (t >> 5) & 1, t4 = (t >> 4) & 1;
    vals[4] = t7            ? -A3 : A3;
    vals[5] = (t7^t6)       ? -A3 : A3;
    vals[6] = (t7^t6^t5)    ? -A3 : A3;
    vals[7] = (t7^t6^t5^t4) ? -A3 : A3;

    const int lane = t & 63, wv = t >> 6;
    #pragma unroll
    for (int i = 0; i < 8; ++i) {
        float v = vals[i];
        #pragma unroll
        for (int off = 32; off; off >>= 1) v += __shfl_xor(v, off, 64);
        if (lane == 0) sred[wv * 8 + i] = v;
    }
    __syncthreads();
    if (t < 8) {
        const float r = sred[t] + sred[8 + t] + sred[16 + t] + sred[24 + t];
        out[b * 8 + t] = r * 3.14159265358979323846f;
    }
}

extern "C" void kernel_launch(void* const* d_in, const int* in_sizes, int n_in,
                              void* d_out, int out_size, void* d_ws, size_t ws_size,
                              hipStream_t stream) {
    const float* x = (const float*)d_in[0];   // [4096, 2]
    const float* w = (const float*)d_in[1];   // [4, 12, 3]
    float* out = (float*)d_out;               // [4096, 8]
    qnn_kernel<<<4096, 256, 0, stream>>>(x, w, out);
}